// Round 1
// baseline (361.491 us; speedup 1.0000x reference)
//
#include <hip/hip_runtime.h>

// Problem constants (fixed by the reference)
#define S_LEN 2048
#define NH 16
#define DHE 64
#define DMODEL 1024

typedef __bf16 bf16x8 __attribute__((ext_vector_type(8)));
typedef short s16x8 __attribute__((ext_vector_type(8)));
typedef float f32x4 __attribute__((ext_vector_type(4)));

__device__ __forceinline__ unsigned short f2bf(float f) {
  unsigned u = __float_as_uint(f);
  u += 0x7FFFu + ((u >> 16) & 1u);   // RNE
  return (unsigned short)(u >> 16);
}
__device__ __forceinline__ float bf2f(unsigned short s) {
  return __uint_as_float(((unsigned)s) << 16);
}
__device__ __forceinline__ f32x4 mfma16(bf16x8 a, bf16x8 b, f32x4 c) {
  return __builtin_amdgcn_mfma_f32_16x16x32_bf16(a, b, c, 0, 0, 0);
}

// ---------------- fp32 -> bf16 elementwise ----------------
__global__ __launch_bounds__(256) void cvt_bf16_kernel(const float* __restrict__ src,
                                                       unsigned short* __restrict__ dst,
                                                       int n4) {
  int i = blockIdx.x * 256 + threadIdx.x;
  if (i < n4) {
    float4 f = ((const float4*)src)[i];
    ushort4 o;
    o.x = f2bf(f.x); o.y = f2bf(f.y); o.z = f2bf(f.z); o.w = f2bf(f.w);
    ((ushort4*)dst)[i] = o;
  }
}

// ---------------- fp32 [K,N] -> bf16 [N,K] transpose ----------------
__global__ __launch_bounds__(256) void transpose_cvt_kernel(const float* __restrict__ W,
                                                            unsigned short* __restrict__ Wt,
                                                            int K, int N) {
  __shared__ float tile[64][65];
  int k0 = blockIdx.y * 64, n0 = blockIdx.x * 64;
  int tx = threadIdx.x & 63, ty = threadIdx.x >> 6;   // ty 0..3
  for (int j = 0; j < 16; ++j) {
    int k = ty * 16 + j;
    tile[k][tx] = W[(size_t)(k0 + k) * N + n0 + tx];
  }
  __syncthreads();
  for (int j = 0; j < 16; ++j) {
    int n = ty * 16 + j;
    Wt[(size_t)(n0 + n) * K + k0 + tx] = f2bf(tile[tx][n]);
  }
}

// ---------------- bf16 GEMM: C[M,N] = A[M,K] * Bt[N,K]^T (m97 pattern) ----------------
// 128x128 tile, BK=32, 4 waves in 2x2, each wave 4x4 subtiles of 16x16x32 MFMA.
__global__ __launch_bounds__(256) void gemm_bt_kernel(const unsigned short* __restrict__ A,
                                                      const unsigned short* __restrict__ Bt,
                                                      unsigned short* __restrict__ C,
                                                      int M, int N, int K) {
  __shared__ unsigned short Ald[128 * 40];  // pitch 40 bf16 = 80 B (16B aligned, 2-way banks)
  __shared__ unsigned short Bld[128 * 40];
  const int tid = threadIdx.x;
  const int wave = tid >> 6, lane = tid & 63;
  const int quad = lane >> 4, l16 = lane & 15;
  const int m0 = blockIdx.y * 128, n0 = blockIdx.x * 128;
  const int wm = (wave >> 1) * 64, wn = (wave & 1) * 64;

  f32x4 acc[4][4] = {};

  for (int ko = 0; ko < K; ko += 32) {
    __syncthreads();
    // stage: 128 rows x 32 cols bf16 each = 512 uint4 per tile; 2 per thread per tile
    for (int i = 0; i < 2; ++i) {
      int flat = tid + 256 * i;        // 0..511
      int row = flat >> 2, c = flat & 3;
      *(uint4*)&Ald[row * 40 + c * 8] =
          *(const uint4*)(A + (size_t)(m0 + row) * K + ko + c * 8);
      *(uint4*)&Bld[row * 40 + c * 8] =
          *(const uint4*)(Bt + (size_t)(n0 + row) * K + ko + c * 8);
    }
    __syncthreads();
    bf16x8 af[4], bfv[4];
    for (int t = 0; t < 4; ++t) {
      af[t]  = *(const bf16x8*)&Ald[(wm + t * 16 + l16) * 40 + quad * 8];
      bfv[t] = *(const bf16x8*)&Bld[(wn + t * 16 + l16) * 40 + quad * 8];
    }
    for (int mi = 0; mi < 4; ++mi)
      for (int ni = 0; ni < 4; ++ni)
        acc[mi][ni] = mfma16(af[mi], bfv[ni], acc[mi][ni]);
  }

  // epilogue: C/D layout col=lane&15, row=quad*4+r
  for (int mi = 0; mi < 4; ++mi)
    for (int ni = 0; ni < 4; ++ni)
      for (int r = 0; r < 4; ++r) {
        int m = m0 + wm + mi * 16 + quad * 4 + r;
        int n = n0 + wn + ni * 16 + l16;
        C[(size_t)m * N + n] = f2bf(acc[mi][ni][r]);
      }
}

// ---------------- fused flash attention ----------------
// grid: (S/64, H, B); block 256 = 4 waves; wave w handles Q rows q0+w*16 .. +15.
// QK head-dim = 128 (tok 0..63 | pos 64..127), V head-dim 64. Online softmax.
__global__ __launch_bounds__(256) void flash_kernel(const unsigned short* __restrict__ tok,
                                                    const unsigned short* __restrict__ poskq,
                                                    const float* __restrict__ bias_table,
                                                    float* __restrict__ out) {
  __shared__ unsigned short Kld[64 * 136];   // [key][128 dims], pitch 136 (272 B)
  __shared__ unsigned short Vt[64 * 72];     // [dim][64 keys swizzled], pitch 72 (144 B)
  __shared__ unsigned short Pld[4 * 16 * 72];// per-wave [16 q][64 keys], pitch 72
  __shared__ float biasl[4096];              // delta+2047 -> bias (this head)

  const int tid = threadIdx.x;
  const int wave = tid >> 6, lane = tid & 63;
  const int quad = lane >> 4, l16 = lane & 15;
  const int q0 = blockIdx.x * 64;
  const int h = blockIdx.y;
  const int b = blockIdx.z;

  // Build per-head bias-by-delta table. T5 bucket via exact integer thresholds:
  // for n>=8: b = 8 + #{n>=12,16,23,32,46,64,91,128}, clamp 15  (matches
  // 8 + floor(2*log2(n/8)) mathematically; avoids float-log boundary issues).
  for (int i = tid; i < 4095; i += 256) {
    int delta = i - 2047;       // delta = k - q ; reference n = q - k = -delta
    int n = -delta;
    int ret = (n < 0) ? 16 : 0;
    int na = (n < 0) ? -n : n;
    int bkt;
    if (na < 8) bkt = na;
    else {
      int s = (na >= 12) + (na >= 16) + (na >= 23) + (na >= 32) +
              (na >= 46) + (na >= 64) + (na >= 91) + (na >= 128);
      bkt = 8 + s;
      if (bkt > 15) bkt = 15;
    }
    bkt += ret;
    biasl[i] = bias_table[(size_t)(2048 + bkt) * NH + h];
  }

  // Load Q fragments (A-operand layout: m=lane&15, k=quad*8+j), scale by 1/sqrt(128)
  const float inv_scale = 0.08838834764831845f;
  bf16x8 qf[4];
  {
    int q = q0 + wave * 16 + l16;
    const unsigned short* tq = tok + (size_t)(b * S_LEN + q) * 3072 + DMODEL + h * DHE;
    const unsigned short* pq = poskq + (size_t)q * 2048 + DMODEL + h * DHE;
    for (int kf = 0; kf < 4; ++kf) {
      const unsigned short* src = (kf < 2) ? (tq + kf * 32 + quad * 8)
                                           : (pq + (kf - 2) * 32 + quad * 8);
      uint4 v = *(const uint4*)src;
      unsigned vv[4] = {v.x, v.y, v.z, v.w};
      s16x8 tmp;
      for (int j = 0; j < 4; ++j) {
        tmp[2 * j]     = (short)f2bf(bf2f((unsigned short)(vv[j] & 0xffffu)) * inv_scale);
        tmp[2 * j + 1] = (short)f2bf(bf2f((unsigned short)(vv[j] >> 16)) * inv_scale);
      }
      qf[kf] = __builtin_bit_cast(bf16x8, tmp);
    }
  }

  float m_r[4], l_r[4];
  f32x4 o_acc[4] = {};
  for (int r = 0; r < 4; ++r) { m_r[r] = -1e30f; l_r[r] = 0.f; }

  const int qbase = q0 + wave * 16 + quad * 4;

  for (int k0i = 0; k0i < S_LEN; k0i += 64) {
    __syncthreads();   // prev-iter LDS reads done (also covers biasl on iter 0)
    // stage K tile: [64 keys][tok 0..63 | pos 64..127]
    for (int i = 0; i < 4; ++i) {
      int flat = tid + 256 * i;       // 0..1023
      int row = flat >> 4, ch = flat & 15;
      const unsigned short* src = (ch < 8)
          ? tok + (size_t)(b * S_LEN + k0i + row) * 3072 + h * DHE + ch * 8
          : poskq + (size_t)(k0i + row) * 2048 + h * DHE + (ch - 8) * 8;
      *(uint4*)&Kld[row * 136 + ch * 8] = *(const uint4*)src;
    }
    // stage V transposed w/ xor swizzle: Vt[dim][key ^ ((dim>>3)<<3)]
    for (int i = 0; i < 2; ++i) {
      int flat = tid + 256 * i;       // 0..511
      int kk = flat >> 3, ch = flat & 7;
      const unsigned short* src =
          tok + (size_t)(b * S_LEN + k0i + kk) * 3072 + 2048 + h * DHE + ch * 8;
      uint4 v = *(const uint4*)src;
      unsigned vv[4] = {v.x, v.y, v.z, v.w};
      int colsw = kk ^ (ch << 3);
      for (int j = 0; j < 4; ++j) {
        Vt[(ch * 8 + 2 * j) * 72 + colsw]     = (unsigned short)(vv[j] & 0xffffu);
        Vt[(ch * 8 + 2 * j + 1) * 72 + colsw] = (unsigned short)(vv[j] >> 16);
      }
    }
    __syncthreads();

    // S = Q*K^T (per wave: 16 q rows x 64 keys), 4 n-tiles x 4 k-frags
    f32x4 s[4] = {};
    for (int t = 0; t < 4; ++t)
      for (int kf = 0; kf < 4; ++kf) {
        bf16x8 kb = *(const bf16x8*)&Kld[(t * 16 + l16) * 136 + kf * 32 + quad * 8];
        s[t] = mfma16(qf[kf], kb, s[t]);
      }

    // + bias, online softmax. C layout: row=quad*4+r, col=l16 (+16t)
    float rm[4];
    for (int r = 0; r < 4; ++r) rm[r] = -1e30f;
    int kcol = k0i + l16;
    for (int t = 0; t < 4; ++t)
      for (int r = 0; r < 4; ++r) {
        int delta = (kcol + t * 16) - (qbase + r);
        float sv = s[t][r] + biasl[delta + 2047];
        s[t][r] = sv;
        rm[r] = fmaxf(rm[r], sv);
      }
    for (int off = 1; off < 16; off <<= 1)
      for (int r = 0; r < 4; ++r)
        rm[r] = fmaxf(rm[r], __shfl_xor(rm[r], off, 64));
    float alpha[4], rs[4];
    for (int r = 0; r < 4; ++r) {
      float mn = fmaxf(m_r[r], rm[r]);
      alpha[r] = __expf(m_r[r] - mn);
      m_r[r] = mn;
      rs[r] = 0.f;
    }
    for (int t = 0; t < 4; ++t)
      for (int r = 0; r < 4; ++r) {
        float pv = __expf(s[t][r] - m_r[r]);
        s[t][r] = pv;
        rs[r] += pv;
      }
    for (int off = 1; off < 16; off <<= 1)
      for (int r = 0; r < 4; ++r)
        rs[r] += __shfl_xor(rs[r], off, 64);
    for (int r = 0; r < 4; ++r) l_r[r] = l_r[r] * alpha[r] + rs[r];
    for (int d = 0; d < 4; ++d)
      for (int r = 0; r < 4; ++r)
        o_acc[d][r] *= alpha[r];

    // P -> LDS (C layout) -> A-operand layout, bf16
    unsigned short* Pw = &Pld[wave * 16 * 72];
    for (int t = 0; t < 4; ++t)
      for (int r = 0; r < 4; ++r)
        Pw[(quad * 4 + r) * 72 + t * 16 + l16] = f2bf(s[t][r]);
    // (same-wave write->read; compiler inserts lgkmcnt wait)
    for (int kf = 0; kf < 2; ++kf) {
      bf16x8 pa = *(const bf16x8*)&Pw[l16 * 72 + kf * 32 + quad * 8];
      for (int d = 0; d < 4; ++d) {
        int n = d * 16 + l16;
        int colbase = (kf * 32 + quad * 8) ^ ((n >> 3) << 3);
        bf16x8 vb = *(const bf16x8*)&Vt[n * 72 + colbase];
        o_acc[d] = mfma16(pa, vb, o_acc[d]);
      }
    }
  }

  // epilogue: out[b, q, h*64 + dim] fp32
  for (int r = 0; r < 4; ++r) {
    float inv_l = 1.f / l_r[r];
    int q = qbase + r;
    for (int d = 0; d < 4; ++d)
      out[(size_t)(b * S_LEN + q) * DMODEL + h * DHE + d * 16 + l16] = o_acc[d][r] * inv_l;
  }
}

extern "C" void kernel_launch(void* const* d_in, const int* in_sizes, int n_in,
                              void* d_out, int out_size, void* d_ws, size_t ws_size,
                              hipStream_t stream) {
  (void)in_sizes; (void)n_in; (void)out_size; (void)ws_size;
  const float* x          = (const float*)d_in[0];   // [2,2048,1024]
  const float* pos_embed  = (const float*)d_in[1];   // [2048,1024]
  const float* W_pos_kq   = (const float*)d_in[2];   // [1024,2048]
  const float* W_tok_kqv  = (const float*)d_in[3];   // [1024,3072]
  const float* bias_table = (const float*)d_in[4];   // [4096,16]
  float* out = (float*)d_out;

  // workspace layout (bf16 elements), total ~54 MB
  unsigned short* x_bf     = (unsigned short*)d_ws;                 // 4096x1024
  unsigned short* pos_bf   = x_bf   + (size_t)4096 * 1024;          // 2048x1024
  unsigned short* wt_tok   = pos_bf + (size_t)2048 * 1024;          // 3072x1024 (W_tok^T)
  unsigned short* wt_pos   = wt_tok + (size_t)3072 * 1024;          // 2048x1024 (W_pos^T)
  unsigned short* tok_bf   = wt_pos + (size_t)2048 * 1024;          // 4096x3072
  unsigned short* poskq_bf = tok_bf + (size_t)4096 * 3072;          // 2048x2048

  cvt_bf16_kernel<<<(4096 * 1024 / 4 + 255) / 256, 256, 0, stream>>>(x, x_bf, 4096 * 1024 / 4);
  cvt_bf16_kernel<<<(2048 * 1024 / 4 + 255) / 256, 256, 0, stream>>>(pos_embed, pos_bf, 2048 * 1024 / 4);
  transpose_cvt_kernel<<<dim3(3072 / 64, 1024 / 64), 256, 0, stream>>>(W_tok_kqv, wt_tok, 1024, 3072);
  transpose_cvt_kernel<<<dim3(2048 / 64, 1024 / 64), 256, 0, stream>>>(W_pos_kq, wt_pos, 1024, 2048);

  gemm_bt_kernel<<<dim3(3072 / 128, 4096 / 128), 256, 0, stream>>>(x_bf, wt_tok, tok_bf, 4096, 3072, 1024);
  gemm_bt_kernel<<<dim3(2048 / 128, 2048 / 128), 256, 0, stream>>>(pos_bf, wt_pos, poskq_bf, 2048, 2048, 1024);

  flash_kernel<<<dim3(S_LEN / 64, NH, 2), 256, 0, stream>>>(tok_bf, poskq_bf, bias_table, out);
}

// Round 2
// 265.725 us; speedup vs baseline: 1.3604x; 1.3604x over previous
//
#include <hip/hip_runtime.h>

#define S_LEN 2048
#define NH 16
#define DHE 64

typedef __bf16 bf16x8 __attribute__((ext_vector_type(8)));
typedef short s16x8 __attribute__((ext_vector_type(8)));
typedef float f32x4 __attribute__((ext_vector_type(4)));

__device__ __forceinline__ unsigned short f2bf(float f) {  // RNE
  unsigned u = __float_as_uint(f);
  u += 0x7FFFu + ((u >> 16) & 1u);
  return (unsigned short)(u >> 16);
}
__device__ __forceinline__ float bf2f(unsigned short s) {
  return __uint_as_float(((unsigned)s) << 16);
}
__device__ __forceinline__ f32x4 mfma16(bf16x8 a, bf16x8 b, f32x4 c) {
  return __builtin_amdgcn_mfma_f32_16x16x32_bf16(a, b, c, 0, 0, 0);
}
__device__ __forceinline__ void glds16(const void* g, void* l) {
  __builtin_amdgcn_global_load_lds(
      (const __attribute__((address_space(1))) unsigned int*)g,
      (__attribute__((address_space(3))) unsigned int*)l, 16, 0, 0);
}

// ---------------- fp32 -> bf16 elementwise ----------------
__global__ __launch_bounds__(256) void cvt_bf16_kernel(const float* __restrict__ src,
                                                       unsigned short* __restrict__ dst,
                                                       int n4) {
  int i = blockIdx.x * 256 + threadIdx.x;
  if (i < n4) {
    float4 f = ((const float4*)src)[i];
    ushort4 o;
    o.x = f2bf(f.x); o.y = f2bf(f.y); o.z = f2bf(f.z); o.w = f2bf(f.w);
    ((ushort4*)dst)[i] = o;
  }
}

// ---------------- fp32 [K,N] -> bf16 [N,K] transpose ----------------
__global__ __launch_bounds__(256) void transpose_cvt_kernel(const float* __restrict__ W,
                                                            unsigned short* __restrict__ Wt,
                                                            int K, int N) {
  __shared__ float tile[64][65];
  int k0 = blockIdx.y * 64, n0 = blockIdx.x * 64;
  int tx = threadIdx.x & 63, ty = threadIdx.x >> 6;
  for (int j = 0; j < 16; ++j) {
    int k = ty * 16 + j;
    tile[k][tx] = W[(size_t)(k0 + k) * N + n0 + tx];
  }
  __syncthreads();
  for (int j = 0; j < 16; ++j) {
    int n = ty * 16 + j;
    Wt[(size_t)(n0 + n) * K + k0 + tx] = f2bf(tile[tx][n]);
  }
}

// ---------------- bf16 GEMM (m97 pattern w/ global_load_lds) ----------------
__global__ __launch_bounds__(256) void gemm_bt_kernel(const unsigned short* __restrict__ A,
                                                      const unsigned short* __restrict__ Bt,
                                                      unsigned short* __restrict__ C,
                                                      int M, int N, int K) {
  __shared__ unsigned short Ald[128 * 32];
  __shared__ unsigned short Bld[128 * 32];
  const int tid = threadIdx.x;
  const int wave = tid >> 6, lane = tid & 63;
  const int quad = lane >> 4, l16 = lane & 15;
  const int m0 = blockIdx.y * 128, n0 = blockIdx.x * 128;
  const int wm = (wave >> 1) * 64, wn = (wave & 1) * 64;

  f32x4 acc[4][4] = {};
  const int flat0 = tid, flat1 = tid + 256;
  const int r0 = flat0 >> 2, c0 = flat0 & 3;
  const int r1 = flat1 >> 2, c1 = flat1 & 3;

  for (int ko = 0; ko < K; ko += 32) {
    __syncthreads();
    glds16(A + (size_t)(m0 + r0) * K + ko + c0 * 8, &Ald[flat0 * 8]);
    glds16(Bt + (size_t)(n0 + r0) * K + ko + c0 * 8, &Bld[flat0 * 8]);
    glds16(A + (size_t)(m0 + r1) * K + ko + c1 * 8, &Ald[flat1 * 8]);
    glds16(Bt + (size_t)(n0 + r1) * K + ko + c1 * 8, &Bld[flat1 * 8]);
    __syncthreads();
    bf16x8 af[4], bfv[4];
    for (int t = 0; t < 4; ++t) {
      af[t]  = *(const bf16x8*)&Ald[(wm + t * 16 + l16) * 32 + quad * 8];
      bfv[t] = *(const bf16x8*)&Bld[(wn + t * 16 + l16) * 32 + quad * 8];
    }
    for (int mi = 0; mi < 4; ++mi)
      for (int ni = 0; ni < 4; ++ni)
        acc[mi][ni] = mfma16(af[mi], bfv[ni], acc[mi][ni]);
  }

  for (int mi = 0; mi < 4; ++mi)
    for (int ni = 0; ni < 4; ++ni)
      for (int r = 0; r < 4; ++r) {
        int m = m0 + wm + mi * 16 + quad * 4 + r;
        int n = n0 + wn + ni * 16 + l16;
        C[(size_t)m * N + n] = f2bf(acc[mi][ni][r]);
      }
}

// ---------------- bias pre-table: biasG[h][j], j = delta+2047, bf16 ----------------
__global__ __launch_bounds__(256) void bias_pre_kernel(const float* __restrict__ bias_table,
                                                       unsigned short* __restrict__ biasG) {
  int h = blockIdx.x;
  for (int i = threadIdx.x; i < 4608; i += 256) {
    float v = 0.f;
    if (i < 4095) {
      int delta = i - 2047;
      int n = -delta;
      int ret = (n < 0) ? 16 : 0;
      int na = (n < 0) ? -n : n;
      int bkt;
      if (na < 8) bkt = na;
      else {
        int s2 = (na >= 12) + (na >= 16) + (na >= 23) + (na >= 32) +
                 (na >= 46) + (na >= 64) + (na >= 91) + (na >= 128);
        bkt = 8 + s2; if (bkt > 15) bkt = 15;
      }
      bkt += ret;
      v = bias_table[(size_t)(2048 + bkt) * NH + h];
    }
    biasG[h * 4608 + i] = f2bf(v);
  }
}

// ---------------- K fragment-major pre-pack ----------------
// KGt: [bh][tile][(t*2+kf)*64 + quad*16 + l16] 16B chunks from tok_k
__global__ __launch_bounds__(256) void kgt_pre_kernel(const unsigned short* __restrict__ tok,
                                                      unsigned short* __restrict__ KGt) {
  int cid = blockIdx.x * 256 + threadIdx.x;          // 32*32*512
  int flat = cid & 511, tile = (cid >> 9) & 31, bh = cid >> 14;
  int b = bh >> 4, h = bh & 15;
  int slot = flat & 63, kfb = (flat >> 6) & 1, t = flat >> 7;
  int l16s = slot & 15, quads = slot >> 4;
  int key = tile * 64 + t * 16 + l16s;
  const unsigned short* src = tok + (size_t)(b * S_LEN + key) * 3072 + h * 64 + kfb * 32 + quads * 8;
  *(uint4*)(KGt + (size_t)cid * 8) = *(const uint4*)src;
}
// KGp: [h][tile][...] from pos_k (batch-independent)
__global__ __launch_bounds__(256) void kgp_pre_kernel(const unsigned short* __restrict__ poskq,
                                                      unsigned short* __restrict__ KGp) {
  int cid = blockIdx.x * 256 + threadIdx.x;          // 16*32*512
  int flat = cid & 511, tile = (cid >> 9) & 31, h = cid >> 14;
  int slot = flat & 63, kfb = (flat >> 6) & 1, t = flat >> 7;
  int l16s = slot & 15, quads = slot >> 4;
  int key = tile * 64 + t * 16 + l16s;
  const unsigned short* src = poskq + (size_t)key * 2048 + h * 64 + kfb * 32 + quads * 8;
  *(uint4*)(KGp + (size_t)cid * 8) = *(const uint4*)src;
}

// ---------------- V^T pre-transpose with xor swizzle ----------------
// VtG[(bh*64+dim)][key'], key' = key ^ ((dim&7)*8)
__global__ __launch_bounds__(256) void vt_pre_kernel(const unsigned short* __restrict__ tok,
                                                     unsigned short* __restrict__ VtG) {
  __shared__ unsigned short Vl[64 * 72];
  int tile = blockIdx.x, bh = blockIdx.y;
  int b = bh >> 4, h = bh & 15;
  int tid = threadIdx.x;
  for (int i = 0; i < 2; ++i) {
    int flat = tid + 256 * i;
    int kk = flat >> 3, c = flat & 7;
    *(uint4*)&Vl[kk * 72 + c * 8] =
        *(const uint4*)(tok + (size_t)(b * S_LEN + tile * 64 + kk) * 3072 + 2048 + h * 64 + c * 8);
  }
  __syncthreads();
  for (int i = 0; i < 2; ++i) {
    int flat = tid + 256 * i;
    int dim = flat >> 3, kc = flat & 7;
    union { unsigned short u16[8]; uint4 v; } tmp;
    for (int j = 0; j < 8; ++j) tmp.u16[j] = Vl[(kc * 8 + j) * 72 + dim];
    int colb = (kc * 8) ^ ((dim & 7) * 8);
    *(uint4*)(VtG + (size_t)(bh * 64 + dim) * 2048 + tile * 64 + colb) = tmp.v;
  }
}

// ---------------- fused flash attention v2 ----------------
// grid (S/64, H, B), block 256. Fixed-m softmax (clamp 60), deferred l-reduce.
__global__ __launch_bounds__(256, 4) void flash_kernel(const unsigned short* __restrict__ tokq,
                                                       const unsigned short* __restrict__ posq,
                                                       const unsigned short* __restrict__ KGt,
                                                       const unsigned short* __restrict__ KGp,
                                                       const unsigned short* __restrict__ VtG,
                                                       const unsigned short* __restrict__ biasG,
                                                       float* __restrict__ out) {
  __shared__ unsigned short Kld[16 * 512];   // 16 fragment regions (t*4+kf)
  __shared__ unsigned short Vtl[64 * 64];    // [dim][key'] forced-linear
  __shared__ unsigned short Pld[4 * 1024];   // per-wave 2 regions
  __shared__ unsigned short biasl[2560];     // bf16, idx j = delta + q0 + 63

  const int tid = threadIdx.x;
  const int wave = tid >> 6, lane = tid & 63;
  const int quad = lane >> 4, l16 = lane & 15;
  const int q0 = blockIdx.x * 64;
  const int h = blockIdx.y;
  const int b = blockIdx.z;
  const int bh = b * NH + h;

  // stage bias slice (once; drained by first in-loop barrier)
  {
    int flat = tid;
    if (flat < 320)
      glds16(biasG + (size_t)h * 4608 + (1984 - q0) + flat * 8, &biasl[flat * 8]);
    flat = tid + 256;
    if (flat < 320)
      glds16(biasG + (size_t)h * 4608 + (1984 - q0) + flat * 8, &biasl[flat * 8]);
  }

  // Q fragments, scaled by 1/sqrt(2*DH)
  const float qs = 0.08838834764831845f;
  bf16x8 qf[4];
  {
    int q = q0 + wave * 16 + l16;
    const unsigned short* tq = tokq + (size_t)(b * S_LEN + q) * 3072 + 1024 + h * 64;
    const unsigned short* pq = posq + (size_t)q * 2048 + 1024 + h * 64;
    for (int kf = 0; kf < 4; ++kf) {
      const unsigned short* src = (kf < 2) ? (tq + kf * 32 + quad * 8)
                                           : (pq + (kf - 2) * 32 + quad * 8);
      uint4 v = *(const uint4*)src;
      unsigned vv[4] = {v.x, v.y, v.z, v.w};
      s16x8 tmp;
      for (int j = 0; j < 4; ++j) {
        tmp[2 * j]     = (short)f2bf(bf2f((unsigned short)(vv[j] & 0xffffu)) * qs);
        tmp[2 * j + 1] = (short)f2bf(bf2f((unsigned short)(vv[j] >> 16)) * qs);
      }
      qf[kf] = __builtin_bit_cast(bf16x8, tmp);
    }
  }

  // staging source pointers (loop-invariant parts)
  const unsigned short* kg_src[4];
  unsigned short* kg_dst[4];
  for (int i = 0; i < 4; ++i) {
    int flat = tid + 256 * i;
    int reg = flat >> 6;
    int kfb = reg & 3, t = reg >> 2, slot = flat & 63;
    kg_src[i] = (kfb < 2)
        ? KGt + ((size_t)bh * 32 * 512 + (size_t)(t * 2 + kfb) * 64 + slot) * 8
        : KGp + ((size_t)h * 32 * 512 + (size_t)(t * 2 + (kfb - 2)) * 64 + slot) * 8;
    kg_dst[i] = &Kld[flat * 8];
  }
  const unsigned short* vt_src[2];
  unsigned short* vt_dst[2];
  for (int i = 0; i < 2; ++i) {
    int flat = tid + 256 * i;
    vt_src[i] = VtG + (size_t)(bh * 64 + (flat >> 3)) * 2048 + (flat & 7) * 8;
    vt_dst[i] = &Vtl[flat * 8];
  }

  f32x4 o_acc[4] = {};
  float l_part[4] = {0.f, 0.f, 0.f, 0.f};
  const int qbase = q0 + wave * 16 + quad * 4;
  const int jconst = l16 - wave * 16 - quad * 4 + 63;
  unsigned short* Pw = &Pld[wave * 1024];
  const int pbase = (l16 >> 3) * 128 + quad * 32 + (l16 & 7);

  for (int k0i = 0; k0i < S_LEN; k0i += 64) {
    __syncthreads();
    const int tile = k0i >> 6;
    for (int i = 0; i < 4; ++i) glds16(kg_src[i] + (size_t)tile * 4096, kg_dst[i]);
    for (int i = 0; i < 2; ++i) glds16(vt_src[i] + k0i, vt_dst[i]);
    __syncthreads();

    // S = Q K^T : reads are base + imm-offset, conflict-free b128
    f32x4 s[4] = {};
    for (int t = 0; t < 4; ++t)
      for (int kf = 0; kf < 4; ++kf) {
        bf16x8 kb = *(const bf16x8*)&Kld[(t * 4 + kf) * 512 + lane * 8];
        s[t] = mfma16(qf[kf], kb, s[t]);
      }

    // fixed-m softmax + P pack (A-fragment-major)
    const int jt = k0i + jconst;
    for (int t = 0; t < 4; ++t)
      for (int r = 0; r < 4; ++r) {
        float bv = bf2f(biasl[jt + t * 16 - r]);
        float arg = fminf(s[t][r] + bv, 60.f);
        float p = __expf(arg);
        l_part[r] += p;
        unsigned u = __float_as_uint(p);
        Pw[pbase + t * 256 + r * 8] = (unsigned short)((u + 0x8000u) >> 16);
      }

    // O += P V
    for (int kf = 0; kf < 2; ++kf) {
      bf16x8 pa = *(const bf16x8*)&Pw[kf * 512 + lane * 8];
      int colb = (kf * 32 + quad * 8) ^ ((l16 & 7) * 8);
      for (int d = 0; d < 4; ++d) {
        bf16x8 vb = *(const bf16x8*)&Vtl[(d * 16 + l16) * 64 + colb];
        o_acc[d] = mfma16(pa, vb, o_acc[d]);
      }
    }
  }

  // one deferred l reduction across the 16 key-lanes
  for (int off = 1; off < 16; off <<= 1)
    for (int r = 0; r < 4; ++r)
      l_part[r] += __shfl_xor(l_part[r], off, 64);

  for (int r = 0; r < 4; ++r) {
    float inv_l = 1.f / l_part[r];
    int q = qbase + r;
    float* op = out + (size_t)(b * S_LEN + q) * 1024 + h * 64;
    for (int d = 0; d < 4; ++d)
      op[d * 16 + l16] = o_acc[d][r] * inv_l;
  }
}

extern "C" void kernel_launch(void* const* d_in, const int* in_sizes, int n_in,
                              void* d_out, int out_size, void* d_ws, size_t ws_size,
                              hipStream_t stream) {
  (void)in_sizes; (void)n_in; (void)out_size; (void)ws_size;
  const float* x          = (const float*)d_in[0];
  const float* pos_embed  = (const float*)d_in[1];
  const float* W_pos_kq   = (const float*)d_in[2];
  const float* W_tok_kqv  = (const float*)d_in[3];
  const float* bias_table = (const float*)d_in[4];
  float* out = (float*)d_out;

  unsigned short* ws = (unsigned short*)d_ws;
  // phase-1 buffers (region A, dead after gemms)
  unsigned short* x_bf   = ws;                        // 4,194,304
  unsigned short* pos_bf = ws + 4194304;              // 2,097,152
  unsigned short* wt_tok = ws + 6291456;              // 3,145,728
  unsigned short* wt_pos = ws + 9437184;              // 2,097,152
  // persistent
  unsigned short* tok_bf   = ws + 11534336;           // 12,582,912
  unsigned short* poskq_bf = ws + 24117248;           // 4,194,304
  // phase-2 overlay of region A
  unsigned short* KGt   = ws;                         // 4,194,304
  unsigned short* KGp   = ws + 4194304;               // 2,097,152
  unsigned short* VtG   = ws + 6291456;               // 4,194,304 (spills into wt_pos, ok)
  unsigned short* biasG = ws + 10485760;              // 73,728

  cvt_bf16_kernel<<<(4096 * 1024 / 4 + 255) / 256, 256, 0, stream>>>(x, x_bf, 4096 * 1024 / 4);
  cvt_bf16_kernel<<<(2048 * 1024 / 4 + 255) / 256, 256, 0, stream>>>(pos_embed, pos_bf, 2048 * 1024 / 4);
  transpose_cvt_kernel<<<dim3(3072 / 64, 1024 / 64), 256, 0, stream>>>(W_tok_kqv, wt_tok, 1024, 3072);
  transpose_cvt_kernel<<<dim3(2048 / 64, 1024 / 64), 256, 0, stream>>>(W_pos_kq, wt_pos, 1024, 2048);

  gemm_bt_kernel<<<dim3(24, 32), 256, 0, stream>>>(x_bf, wt_tok, tok_bf, 4096, 3072, 1024);
  gemm_bt_kernel<<<dim3(16, 16), 256, 0, stream>>>(pos_bf, wt_pos, poskq_bf, 2048, 2048, 1024);

  kgt_pre_kernel<<<2048, 256, 0, stream>>>(tok_bf, KGt);
  kgp_pre_kernel<<<1024, 256, 0, stream>>>(poskq_bf, KGp);
  vt_pre_kernel<<<dim3(32, 32), 256, 0, stream>>>(tok_bf, VtG);
  bias_pre_kernel<<<16, 256, 0, stream>>>(bias_table, biasG);

  flash_kernel<<<dim3(32, NH, 2), 256, 0, stream>>>(tok_bf, poskq_bf, KGt, KGp, VtG, biasG, out);
}